// Round 5
// baseline (294.691 us; speedup 1.0000x reference)
//
#include <hip/hip_runtime.h>
#include <hip/hip_cooperative_groups.h>
#include <stdint.h>

namespace cg = cooperative_groups;

#define HH 2048
#define WW 2048
#define HW (HH * WW)
#define N4 (HW / 4)
#define FB 512        // fine histogram bins over fixed [0,1)
#define GB 256        // cooperative grid: 256 blocks x 1024 thr = exactly 1 block/CU (guaranteed resident)
#define NT 1024
#define NTHREADS (GB * NT)   // 262144; hist: 4 iters (262144*4 == N4)

// ws uint32 layout — only words [0..511] used (well inside PROVEN-SAFE 519 words):
// [0..511] fine hist (u32), DEAD after sync S2.
// Accumulators reuse dead bin words, one per 64B cacheline: ctl[320 + 16*k], k=0..5
//   0=recon_low 1=recon_eq 2=sum|dRg| 3=sumRg 4=sum|dL|e^-10|dRg| 5=sum L*e^-10Rg
// (zeroed by block 0 in its own grid-sync epoch after bins die; cdf lives only in LDS)

__device__ __forceinline__ float gray_pil(float r, float g, float b) {
    float qr = floorf(fminf(fmaxf(r, 0.f), 1.f) * 255.f);
    float qg = floorf(fminf(fmaxf(g, 0.f), 1.f) * 255.f);
    float qb = floorf(fminf(fmaxf(b, 0.f), 1.f) * 255.f);
    // all terms integers < 2^24: exact in fp32
    float s = floorf((qr * 19595.f + qg * 38470.f + qb * 7471.f + 32768.f) * (1.f / 65536.f));
    return s * (1.f / 255.f);
}

__device__ __forceinline__ void px(float r0, float r1, float r2,
                                   float i0, float i1, float i2, float l,
                                   float& rgp, float& lp,
                                   const float* __restrict__ scdf, float gmin, float inv_dw,
                                   float& a0, float& a1, float& a2,
                                   float& a3, float& a4, float& a5) {
    a0 += fabsf(r0 * l - i0) + fabsf(r1 * l - i1) + fabsf(r2 * l - i2);
    float rmax = fmaxf(r0, fmaxf(r1, r2));
    float imax = fmaxf(i0, fmaxf(i1, i2));
    float t = (imax - gmin) * inv_dw;
    t = fmaxf(t, 0.f);
    int bi = (int)t;
    float eq;
    if (bi >= 255) eq = scdf[255];
    else {
        float fr = t - (float)bi;
        eq = scdf[bi] + fr * (scdf[bi + 1] - scdf[bi]);
    }
    a1 += fabsf(rmax - eq);
    float rg = gray_pil(r0, r1, r2);
    a3 += rg;
    a5 += l * __expf(-10.f * rg);
    float drg = fabsf(rg - rgp);
    a2 += drg;
    a4 += fabsf(l - lp) * __expf(-10.f * drg);
    rgp = rg;
    lp = l;
}

// One 2-row strip (rows h0, h0+1; prologue row h0-1). Round-2-proven liveness: no spills.
__device__ __forceinline__ void do_strip(int h0, int w,
                                         const float* __restrict__ im, const float* __restrict__ R,
                                         const float* __restrict__ L,
                                         const float* __restrict__ scdf, float gmin, float inv_dw,
                                         float& a0, float& a1, float& a2,
                                         float& a3, float& a4, float& a5) {
    float rgp[4], lp[4];
    if (h0 > 0) {
        int p = (h0 - 1) * WW + w;
        float4 Ra = *(const float4*)(R + p);
        float4 Rb = *(const float4*)(R + p + HW);
        float4 Rc = *(const float4*)(R + p + 2 * HW);
        float4 Lv = *(const float4*)(L + p);
        rgp[0] = gray_pil(Ra.x, Rb.x, Rc.x); lp[0] = Lv.x;
        rgp[1] = gray_pil(Ra.y, Rb.y, Rc.y); lp[1] = Lv.y;
        rgp[2] = gray_pil(Ra.z, Rb.z, Rc.z); lp[2] = Lv.z;
        rgp[3] = gray_pil(Ra.w, Rb.w, Rc.w); lp[3] = Lv.w;
    } else {
        rgp[0] = rgp[1] = rgp[2] = rgp[3] = 0.f;
        lp[0] = lp[1] = lp[2] = lp[3] = 0.f;
    }
#pragma unroll
    for (int h = h0; h < h0 + 2; ++h) {
        int p = h * WW + w;
        float4 r0 = *(const float4*)(R + p);
        float4 r1 = *(const float4*)(R + p + HW);
        float4 r2 = *(const float4*)(R + p + 2 * HW);
        float4 i0 = *(const float4*)(im + p);
        float4 i1 = *(const float4*)(im + p + HW);
        float4 i2 = *(const float4*)(im + p + 2 * HW);
        float4 lv = *(const float4*)(L + p);
        px(r0.x, r1.x, r2.x, i0.x, i1.x, i2.x, lv.x, rgp[0], lp[0], scdf, gmin, inv_dw, a0, a1, a2, a3, a4, a5);
        px(r0.y, r1.y, r2.y, i0.y, i1.y, i2.y, lv.y, rgp[1], lp[1], scdf, gmin, inv_dw, a0, a1, a2, a3, a4, a5);
        px(r0.z, r1.z, r2.z, i0.z, i1.z, i2.z, lv.z, rgp[2], lp[2], scdf, gmin, inv_dw, a0, a1, a2, a3, a4, a5);
        px(r0.w, r1.w, r2.w, i0.w, i1.w, i2.w, lv.w, rgp[3], lp[3], scdf, gmin, inv_dw, a0, a1, a2, a3, a4, a5);
    }
    if (h0 + 2 == HH) {  // boundary at h = 2048: |0 - x[2047]|
#pragma unroll
        for (int j = 0; j < 4; ++j) {
            a2 += rgp[j];
            a4 += lp[j] * __expf(-10.f * rgp[j]);
        }
    }
}

__global__ __launch_bounds__(NT, 4)
void fused_k(const float* __restrict__ im, const float* __restrict__ R,
             const float* __restrict__ L, uint32_t* __restrict__ ctl,
             float* __restrict__ out) {
    cg::grid_group grid = cg::this_grid();
    __shared__ uint32_t lh[FB];
    __shared__ uint32_t sc[256];
    __shared__ float scdf[256];
    __shared__ uint32_t smm[2];
    __shared__ float red[6][16];
    int t = threadIdx.x;
    int bid = blockIdx.x;
    int tid = bid * NT + t;

    // ================= phase 1: fine hist of per-pixel channel max =================
    if (t < FB) lh[t] = 0u;
    __syncthreads();
    {
        const float4* im4 = (const float4*)im;
        for (int k = 0; k < 4; ++k) {           // 262144 threads * 4 == N4 exactly
            int i = tid + k * NTHREADS;
            float4 a = im4[i], b = im4[i + N4], c = im4[i + 2 * N4];
            float m0 = fmaxf(a.x, fmaxf(b.x, c.x));
            float m1 = fmaxf(a.y, fmaxf(b.y, c.y));
            float m2 = fmaxf(a.z, fmaxf(b.z, c.z));
            float m3 = fmaxf(a.w, fmaxf(b.w, c.w));
            int b0 = (int)(m0 * (float)FB); b0 = b0 < 0 ? 0 : (b0 > FB - 1 ? FB - 1 : b0);
            int b1 = (int)(m1 * (float)FB); b1 = b1 < 0 ? 0 : (b1 > FB - 1 ? FB - 1 : b1);
            int b2 = (int)(m2 * (float)FB); b2 = b2 < 0 ? 0 : (b2 > FB - 1 ? FB - 1 : b2);
            int b3 = (int)(m3 * (float)FB); b3 = b3 < 0 ? 0 : (b3 > FB - 1 ? FB - 1 : b3);
            atomicAdd(&lh[b0], 1u); atomicAdd(&lh[b1], 1u);
            atomicAdd(&lh[b2], 1u); atomicAdd(&lh[b3], 1u);
        }
    }
    __syncthreads();
    // paired 64-bit flush (halves RMW count; per-bin totals < 2^32 so no cross-carry),
    // rotated start per block to spread same-line queueing in L2.
    if (t < 256) {
        int pr = (t + bid * 7) & 255;
        unsigned long long v = (unsigned long long)lh[2 * pr]
                             | ((unsigned long long)lh[2 * pr + 1] << 32);
        if (v) atomicAdd((unsigned long long*)&ctl[2 * pr], v);
    }
    grid.sync();   // S1: global fine hist complete (device-scope acquire/release)

    // ========== phase 2: per-block cdf derivation (numerics identical to prior rounds) ==========
    if (t < FB) lh[t] = ctl[t];       // plain loads are coherent after grid.sync
    if (t < 256) sc[t] = 0u;
    if (t == 0) { smm[0] = FB; smm[1] = 0u; }
    __syncthreads();
    if (t < FB && lh[t]) { atomicMin(&smm[0], (uint32_t)t); atomicMax(&smm[1], (uint32_t)t); }
    __syncthreads();
    float gmin = (float)smm[0] * (1.0f / (float)FB);         // left edge of first nonempty fine bin
    float gmax = (float)(smm[1] + 1u) * (1.0f / (float)FB);  // right edge of last nonempty fine bin
    float inv_dw = 256.0f / (gmax - gmin);
    if (t < FB && lh[t]) {
        float c = ((float)t + 0.5f) * (1.0f / (float)FB);    // fine-bin center
        int q = (int)((c - gmin) * inv_dw);
        q = q < 0 ? 0 : (q > 255 ? 255 : q);
        atomicAdd(&sc[q], lh[t]);
    }
    __syncthreads();
    for (int d = 1; d < 256; d <<= 1) {                      // deterministic integer scan
        uint32_t v = (t < 256 && t >= d) ? sc[t - d] : 0u;
        __syncthreads();
        if (t < 256) sc[t] += v;
        __syncthreads();
    }
    if (t < 256) scdf[t] = (float)((double)sc[t] * (1.0 / (double)HW));
    __syncthreads();
    grid.sync();   // S2: every block has copied bins -> global bin words are dead
    if (bid == 0 && t < 6) ctl[320 + t * 16] = 0u;   // zero acc slots (6 distinct cachelines)
    grid.sync();   // S3: acc slots initialized before any accumulation

    // ================= phase 3: streaming main pass =================
    int w = (tid & 511) * 4;      // 4 adjacent columns per thread
    int sb = tid >> 9;            // strip-slot 0..511; thread owns strips sb and sb+512
    float a0 = 0.f, a1 = 0.f, a2 = 0.f, a3 = 0.f, a4 = 0.f, a5 = 0.f;
    do_strip(2 * sb,        w, im, R, L, scdf, gmin, inv_dw, a0, a1, a2, a3, a4, a5);
    do_strip(2 * sb + 1024, w, im, R, L, scdf, gmin, inv_dw, a0, a1, a2, a3, a4, a5);

    for (int off = 32; off; off >>= 1) {
        a0 += __shfl_down(a0, off);
        a1 += __shfl_down(a1, off);
        a2 += __shfl_down(a2, off);
        a3 += __shfl_down(a3, off);
        a4 += __shfl_down(a4, off);
        a5 += __shfl_down(a5, off);
    }
    int lane = t & 63, wv = t >> 6;
    if (lane == 0) {
        red[0][wv] = a0; red[1][wv] = a1; red[2][wv] = a2;
        red[3][wv] = a3; red[4][wv] = a4; red[5][wv] = a5;
    }
    __syncthreads();
    if (t == 0) {
        float s0 = 0, s1 = 0, s2 = 0, s3 = 0, s4 = 0, s5 = 0;
        for (int k = 0; k < 16; k++) {
            s0 += red[0][k]; s1 += red[1][k]; s2 += red[2][k];
            s3 += red[3][k]; s4 += red[4][k]; s5 += red[5][k];
        }
        float* accf = (float*)ctl;
        atomicAdd(&accf[320], s0);  // 6 accs on 6 distinct 64B lines: chains pipeline in parallel
        atomicAdd(&accf[336], s1);
        atomicAdd(&accf[352], s2);
        atomicAdd(&accf[368], s3);
        atomicAdd(&accf[384], s4);
        atomicAdd(&accf[400], s5);
    }
    grid.sync();   // S4: all accumulation visible

    if (bid == 0 && t == 0) {
        const float* accf = (const float*)ctl;
        float v0 = accf[320], v1 = accf[336], v2 = accf[352];
        float v3 = accf[368], v4 = accf[384], v5 = accf[400];
        float recon_low = v0 / (3.0f * (float)HW);
        float recon_eq = v1 / (float)HW;
        float denom = 2.0f * 2049.0f * 2050.0f;
        float r_smooth = (v2 + 2.f * v3) / denom;
        float ismooth = (v4 + 2.f * v5) / denom;
        out[0] = recon_low + 0.1f * ismooth + 0.1f * recon_eq + 0.01f * r_smooth;
    }
}

extern "C" void kernel_launch(void* const* d_in, const int* in_sizes, int n_in,
                              void* d_out, int out_size, void* d_ws, size_t ws_size,
                              hipStream_t stream) {
    const float* im = (const float*)d_in[0];
    const float* R = (const float*)d_in[1];
    const float* L = (const float*)d_in[2];
    float* out = (float*)d_out;
    uint32_t* ctl = (uint32_t*)d_ws;

    hipMemsetAsync(d_ws, 0, FB * 4, stream);  // zero fine-hist bins (graph-capturable node)
    void* args[] = {(void*)&im, (void*)&R, (void*)&L, (void*)&ctl, (void*)&out};
    hipLaunchCooperativeKernel((const void*)fused_k, dim3(GB), dim3(NT), args, 0, stream);
}

// Round 6
// 170.218 us; speedup vs baseline: 1.7313x; 1.7313x over previous
//
#include <hip/hip_runtime.h>
#include <stdint.h>

#define HH 2048
#define WW 2048
#define HW (HH * WW)
#define N4 (HW / 4)
#define FB 512      // fine histogram bins over fixed [0,1)
#define G1H 256     // hist blocks (1024 thr, 4 hoisted iters: 256*1024*4 == N4)
#define G3M 512     // main blocks (1024 thr): exact round-2 shape, one 2-row strip per thread
#define STRIDE (G1H * 1024)

// ws uint32 layout (always-used region = 519 words, PROVEN-SAFE):
// [0..511]   fine hist (u32); AFTER hist_k last block: [0..255]=cdf(float), [256]=gmin, [257]=gmax
// [512..517] legacy acc floats (fallback finalize path only)
// [518]      SHARED done counter: hist_k blocks add 1 (last sees G1H-1), main_k blocks add 1
//            (last sees G1H+G3M-1)
// [520..520+6*G3M) OPTIONAL per-block partials (512 blocks x 6 floats) — host-gated on ws_size

__device__ __forceinline__ float gray_pil(float r, float g, float b) {
    float qr = floorf(fminf(fmaxf(r, 0.f), 1.f) * 255.f);
    float qg = floorf(fminf(fmaxf(g, 0.f), 1.f) * 255.f);
    float qb = floorf(fminf(fmaxf(b, 0.f), 1.f) * 255.f);
    // all terms integers < 2^24: exact in fp32
    float s = floorf((qr * 19595.f + qg * 38470.f + qb * 7471.f + 32768.f) * (1.f / 65536.f));
    return s * (1.f / 255.f);
}

// ---------------- K1: fine histogram + (last block) cdf derivation ----------------
__global__ __launch_bounds__(1024, 4)
void hist_k(const float* __restrict__ im, uint32_t* __restrict__ ctl) {
    __shared__ uint32_t lh[FB];
    __shared__ uint32_t sc[256];
    __shared__ uint32_t smm[2];
    __shared__ uint32_t lastf;
    int t = threadIdx.x;
    if (t < FB) lh[t] = 0u;
    __syncthreads();

    const float4* im4 = (const float4*)im;
    int tid = blockIdx.x * 1024 + t;
    // hoisted loads: 12 independent float4 in flight before any compute (round-4 proven)
    float4 A0 = im4[tid],              B0 = im4[tid + N4],              C0 = im4[tid + 2 * N4];
    float4 A1 = im4[tid + STRIDE],     B1 = im4[tid + STRIDE + N4],     C1 = im4[tid + STRIDE + 2 * N4];
    float4 A2 = im4[tid + 2 * STRIDE], B2 = im4[tid + 2 * STRIDE + N4], C2 = im4[tid + 2 * STRIDE + 2 * N4];
    float4 A3 = im4[tid + 3 * STRIDE], B3 = im4[tid + 3 * STRIDE + N4], C3 = im4[tid + 3 * STRIDE + 2 * N4];

#define HBIN(a, b, c) { \
        float m0 = fmaxf(a.x, fmaxf(b.x, c.x)); \
        float m1 = fmaxf(a.y, fmaxf(b.y, c.y)); \
        float m2 = fmaxf(a.z, fmaxf(b.z, c.z)); \
        float m3 = fmaxf(a.w, fmaxf(b.w, c.w)); \
        int b0 = (int)(m0 * (float)FB); b0 = b0 < 0 ? 0 : (b0 > FB - 1 ? FB - 1 : b0); \
        int b1 = (int)(m1 * (float)FB); b1 = b1 < 0 ? 0 : (b1 > FB - 1 ? FB - 1 : b1); \
        int b2 = (int)(m2 * (float)FB); b2 = b2 < 0 ? 0 : (b2 > FB - 1 ? FB - 1 : b2); \
        int b3 = (int)(m3 * (float)FB); b3 = b3 < 0 ? 0 : (b3 > FB - 1 ? FB - 1 : b3); \
        atomicAdd(&lh[b0], 1u); atomicAdd(&lh[b1], 1u); \
        atomicAdd(&lh[b2], 1u); atomicAdd(&lh[b3], 1u); }
    HBIN(A0, B0, C0)
    HBIN(A1, B1, C1)
    HBIN(A2, B2, C2)
    HBIN(A3, B3, C3)
#undef HBIN

    __syncthreads();
    // paired 64-bit flush (halves device RMWs; per-bin totals < 2^32 so no cross-carry),
    // rotated start per block to spread same-line queueing (round-5 proven numerics).
    if (t < 256) {
        int pr = (t + blockIdx.x * 7) & 255;
        unsigned long long v = (unsigned long long)lh[2 * pr]
                             | ((unsigned long long)lh[2 * pr + 1] << 32);
        if (v) atomicAdd((unsigned long long*)&ctl[2 * pr], v);
    }
    __syncthreads();
    if (t == 0) {
        __threadfence();
        lastf = (atomicAdd(&ctl[518], 1u) == G1H - 1) ? 1u : 0u;
    }
    __syncthreads();
    if (!lastf) return;

    // ---- last block only: derive 256-bin cdf (exact numerics of the original cdf_k) ----
    if (t < FB) lh[t] = atomicAdd(&ctl[t], 0u);   // device-scope read: sees all flush atomics
    if (t < 256) sc[t] = 0u;
    if (t == 0) { smm[0] = FB; smm[1] = 0u; }
    __syncthreads();
    if (t < FB && lh[t]) { atomicMin(&smm[0], (uint32_t)t); atomicMax(&smm[1], (uint32_t)t); }
    __syncthreads();
    float gmin = (float)smm[0] * (1.0f / (float)FB);         // left edge of first nonempty fine bin
    float gmax = (float)(smm[1] + 1u) * (1.0f / (float)FB);  // right edge of last nonempty fine bin
    float inv_dw = 256.0f / (gmax - gmin);
    if (t < FB && lh[t]) {
        float c = ((float)t + 0.5f) * (1.0f / (float)FB);    // fine-bin center
        int q = (int)((c - gmin) * inv_dw);
        q = q < 0 ? 0 : (q > 255 ? 255 : q);
        atomicAdd(&sc[q], lh[t]);
    }
    __syncthreads();
    // inclusive integer scan -> cdf (barriers unconditional for all 1024 threads)
    for (int d = 1; d < 256; d <<= 1) {
        uint32_t v = (t < 256 && t >= d) ? sc[t - d] : 0u;
        __syncthreads();
        if (t < 256) sc[t] += v;
        __syncthreads();
    }
    float* cf = (float*)ctl;
    if (t < 256) cf[t] = (float)((double)sc[t] * (1.0 / (double)HW));
    if (t == 0) { cf[256] = gmin; cf[257] = gmax; }
}

// ---------------- K2: fused main pass + finalize ----------------
__device__ __forceinline__ void px(float r0, float r1, float r2,
                                   float i0, float i1, float i2, float l,
                                   float& rgp, float& lp,
                                   const float* __restrict__ scdf, float gmin, float inv_dw,
                                   float& a0, float& a1, float& a2,
                                   float& a3, float& a4, float& a5) {
    a0 += fabsf(r0 * l - i0) + fabsf(r1 * l - i1) + fabsf(r2 * l - i2);
    float rmax = fmaxf(r0, fmaxf(r1, r2));
    float imax = fmaxf(i0, fmaxf(i1, i2));
    float t = (imax - gmin) * inv_dw;
    t = fmaxf(t, 0.f);
    int bi = (int)t;
    float eq;
    if (bi >= 255) eq = scdf[255];
    else {
        float fr = t - (float)bi;
        eq = scdf[bi] + fr * (scdf[bi + 1] - scdf[bi]);
    }
    a1 += fabsf(rmax - eq);
    float rg = gray_pil(r0, r1, r2);
    a3 += rg;
    a5 += l * __expf(-10.f * rg);
    float drg = fabsf(rg - rgp);
    a2 += drg;
    a4 += fabsf(l - lp) * __expf(-10.f * drg);
    rgp = rg;
    lp = l;
}

// EXACT round-2 shape (the only clean-WRITE configuration measured): 512 blocks x 1024 thr,
// thread t of block b: columns (t&511)*4..+3, rows h0..h0+1 with h0 = b*4 + (t>>9)*2.
__global__ __launch_bounds__(1024, 4)
void main_k(const float* __restrict__ im, const float* __restrict__ R,
            const float* __restrict__ L, uint32_t* __restrict__ ctl,
            float* __restrict__ part, int use_part,
            float* __restrict__ out) {
    __shared__ float scdf[256];
    __shared__ float red[6][16];
    __shared__ uint32_t lastf;
    int t = threadIdx.x;

    const float* cf = (const float*)ctl;
    if (t < 256) scdf[t] = cf[t];
    float gmin = cf[256];
    float gmax = cf[257];
    float inv_dw = 256.0f / (gmax - gmin);
    __syncthreads();

    int w = (t & 511) * 4;                    // 4 adjacent columns per thread
    int h0 = blockIdx.x * 4 + ((t >> 9) * 2); // 2-row strip per thread

    float a0 = 0.f, a1 = 0.f, a2 = 0.f, a3 = 0.f, a4 = 0.f, a5 = 0.f;
    float rgp[4], lp[4];
    if (h0 > 0) {
        int p = (h0 - 1) * WW + w;
        float4 Ra = *(const float4*)(R + p);
        float4 Rb = *(const float4*)(R + p + HW);
        float4 Rc = *(const float4*)(R + p + 2 * HW);
        float4 Lv = *(const float4*)(L + p);
        rgp[0] = gray_pil(Ra.x, Rb.x, Rc.x); lp[0] = Lv.x;
        rgp[1] = gray_pil(Ra.y, Rb.y, Rc.y); lp[1] = Lv.y;
        rgp[2] = gray_pil(Ra.z, Rb.z, Rc.z); lp[2] = Lv.z;
        rgp[3] = gray_pil(Ra.w, Rb.w, Rc.w); lp[3] = Lv.w;
    } else {
        rgp[0] = rgp[1] = rgp[2] = rgp[3] = 0.f;
        lp[0] = lp[1] = lp[2] = lp[3] = 0.f;
    }

#pragma unroll
    for (int h = h0; h < h0 + 2; ++h) {
        int p = h * WW + w;
        float4 r0 = *(const float4*)(R + p);
        float4 r1 = *(const float4*)(R + p + HW);
        float4 r2 = *(const float4*)(R + p + 2 * HW);
        float4 i0 = *(const float4*)(im + p);
        float4 i1 = *(const float4*)(im + p + HW);
        float4 i2 = *(const float4*)(im + p + 2 * HW);
        float4 lv = *(const float4*)(L + p);
        px(r0.x, r1.x, r2.x, i0.x, i1.x, i2.x, lv.x, rgp[0], lp[0], scdf, gmin, inv_dw, a0, a1, a2, a3, a4, a5);
        px(r0.y, r1.y, r2.y, i0.y, i1.y, i2.y, lv.y, rgp[1], lp[1], scdf, gmin, inv_dw, a0, a1, a2, a3, a4, a5);
        px(r0.z, r1.z, r2.z, i0.z, i1.z, i2.z, lv.z, rgp[2], lp[2], scdf, gmin, inv_dw, a0, a1, a2, a3, a4, a5);
        px(r0.w, r1.w, r2.w, i0.w, i1.w, i2.w, lv.w, rgp[3], lp[3], scdf, gmin, inv_dw, a0, a1, a2, a3, a4, a5);
    }
    if (h0 + 2 == HH) {  // boundary at h = 2048: |0 - x[2047]|
#pragma unroll
        for (int j = 0; j < 4; ++j) {
            a2 += rgp[j];
            a4 += lp[j] * __expf(-10.f * rgp[j]);
        }
    }

    for (int off = 32; off; off >>= 1) {
        a0 += __shfl_down(a0, off);
        a1 += __shfl_down(a1, off);
        a2 += __shfl_down(a2, off);
        a3 += __shfl_down(a3, off);
        a4 += __shfl_down(a4, off);
        a5 += __shfl_down(a5, off);
    }
    int lane = t & 63, wv = t >> 6;
    if (lane == 0) {
        red[0][wv] = a0; red[1][wv] = a1; red[2][wv] = a2;
        red[3][wv] = a3; red[4][wv] = a4; red[5][wv] = a5;
    }
    __syncthreads();
    if (t == 0) {
        float s0 = 0, s1 = 0, s2 = 0, s3 = 0, s4 = 0, s5 = 0;
        for (int k = 0; k < 16; k++) {
            s0 += red[0][k]; s1 += red[1][k]; s2 += red[2][k];
            s3 += red[3][k]; s4 += red[4][k]; s5 += red[5][k];
        }
        if (use_part) {
            // chain-free: distinct slot per block (round-4 proven pattern)
            float* pp = part + blockIdx.x * 6;
            atomicExch(&pp[0], s0); atomicExch(&pp[1], s1); atomicExch(&pp[2], s2);
            atomicExch(&pp[3], s3); atomicExch(&pp[4], s4); atomicExch(&pp[5], s5);
        } else {
            float* acc = (float*)(ctl + 512);
            atomicAdd(&acc[0], s0); atomicAdd(&acc[1], s1); atomicAdd(&acc[2], s2);
            atomicAdd(&acc[3], s3); atomicAdd(&acc[4], s4); atomicAdd(&acc[5], s5);
        }
        __threadfence();
        lastf = (atomicAdd(&ctl[518], 1u) == (uint32_t)(G1H + G3M - 1)) ? 1u : 0u;
    }
    __syncthreads();
    if (!lastf) return;

    // ---- last block: final combine ----
    if (use_part) {
        float s0 = 0.f, s1 = 0.f, s2 = 0.f, s3 = 0.f, s4 = 0.f, s5 = 0.f;
        if (t < G3M) {
            float* pp = part + t * 6;
            s0 = atomicAdd(&pp[0], 0.f); s1 = atomicAdd(&pp[1], 0.f); s2 = atomicAdd(&pp[2], 0.f);
            s3 = atomicAdd(&pp[3], 0.f); s4 = atomicAdd(&pp[4], 0.f); s5 = atomicAdd(&pp[5], 0.f);
        }
        for (int off = 32; off; off >>= 1) {
            s0 += __shfl_down(s0, off);
            s1 += __shfl_down(s1, off);
            s2 += __shfl_down(s2, off);
            s3 += __shfl_down(s3, off);
            s4 += __shfl_down(s4, off);
            s5 += __shfl_down(s5, off);
        }
        if (lane == 0) {
            red[0][wv] = s0; red[1][wv] = s1; red[2][wv] = s2;
            red[3][wv] = s3; red[4][wv] = s4; red[5][wv] = s5;
        }
        __syncthreads();
        if (t == 0) {
            float v0 = 0, v1 = 0, v2 = 0, v3 = 0, v4 = 0, v5 = 0;
            for (int k = 0; k < 16; k++) {
                v0 += red[0][k]; v1 += red[1][k]; v2 += red[2][k];
                v3 += red[3][k]; v4 += red[4][k]; v5 += red[5][k];
            }
            float recon_low = v0 / (3.0f * (float)HW);
            float recon_eq = v1 / (float)HW;
            float denom = 2.0f * 2049.0f * 2050.0f;
            float r_smooth = (v2 + 2.f * v3) / denom;
            float ismooth = (v4 + 2.f * v5) / denom;
            out[0] = recon_low + 0.1f * ismooth + 0.1f * recon_eq + 0.01f * r_smooth;
        }
    } else {
        if (t == 0) {
            float* acc = (float*)(ctl + 512);
            float v0 = atomicAdd(&acc[0], 0.f);
            float v1 = atomicAdd(&acc[1], 0.f);
            float v2 = atomicAdd(&acc[2], 0.f);
            float v3 = atomicAdd(&acc[3], 0.f);
            float v4 = atomicAdd(&acc[4], 0.f);
            float v5 = atomicAdd(&acc[5], 0.f);
            float recon_low = v0 / (3.0f * (float)HW);
            float recon_eq = v1 / (float)HW;
            float denom = 2.0f * 2049.0f * 2050.0f;
            float r_smooth = (v2 + 2.f * v3) / denom;
            float ismooth = (v4 + 2.f * v5) / denom;
            out[0] = recon_low + 0.1f * ismooth + 0.1f * recon_eq + 0.01f * r_smooth;
        }
    }
}

extern "C" void kernel_launch(void* const* d_in, const int* in_sizes, int n_in,
                              void* d_out, int out_size, void* d_ws, size_t ws_size,
                              hipStream_t stream) {
    const float* im = (const float*)d_in[0];
    const float* R = (const float*)d_in[1];
    const float* L = (const float*)d_in[2];
    float* out = (float*)d_out;
    uint32_t* ctl = (uint32_t*)d_ws;

    // partials region: words [520 .. 520 + 6*G3M) -> 14368 B total; gate on actual ws_size
    int use_part = (ws_size >= (size_t)((520 + 6 * G3M) * 4 + 32)) ? 1 : 0;
    float* part = (float*)(ctl + 520);

    hipMemsetAsync(d_ws, 0, 519 * 4, stream);  // graph-capturable memset node
    hipLaunchKernelGGL(hist_k, dim3(G1H), dim3(1024), 0, stream, im, ctl);
    hipLaunchKernelGGL(main_k, dim3(G3M), dim3(1024), 0, stream, im, R, L, ctl, part, use_part, out);
}

// Round 7
// 170.143 us; speedup vs baseline: 1.7320x; 1.0004x over previous
//
#include <hip/hip_runtime.h>
#include <stdint.h>

#define HH 2048
#define WW 2048
#define HW (HH * WW)
#define N4 (HW / 4)
#define FB 512      // fine histogram bins over fixed [0,1)
#define G1H 256     // hist blocks (1024 thr, 4 hoisted iters: 256*1024*4 == N4)
#define G3M 512     // main blocks (1024 thr): one 2-row strip per thread (clean-WRITE shape)
#define STRIDE (G1H * 1024)

// ws uint32 layout (always-used region = 519 words, PROVEN-SAFE):
// [0..511]   fine hist (u32); AFTER hist_k last block: [0..255]=cdf(float), [256]=gmin, [257]=gmax
// [512..517] legacy acc floats (fallback finalize path only)
// [518]      SHARED done counter: hist_k blocks add 1 (last sees G1H-1), main_k blocks add 1
//            (last sees G1H+G3M-1)
// [520..520+6*G3M) OPTIONAL per-block partials (512 blocks x 6 floats) — host-gated on ws_size

__device__ __forceinline__ float gray_pil(float r, float g, float b) {
    float qr = floorf(fminf(fmaxf(r, 0.f), 1.f) * 255.f);
    float qg = floorf(fminf(fmaxf(g, 0.f), 1.f) * 255.f);
    float qb = floorf(fminf(fmaxf(b, 0.f), 1.f) * 255.f);
    // all terms integers < 2^24: exact in fp32
    float s = floorf((qr * 19595.f + qg * 38470.f + qb * 7471.f + 32768.f) * (1.f / 65536.f));
    return s * (1.f / 255.f);
}

// ---------------- K1: fine histogram + (last block) cdf derivation ----------------
// launch_bounds(1024,1): free the allocator (arg2 behaves as min-blocks/CU; 2 would cap VGPR=64).
__global__ __launch_bounds__(1024, 1)
void hist_k(const float* __restrict__ im, uint32_t* __restrict__ ctl) {
    __shared__ uint32_t lh[FB];
    __shared__ uint32_t sc[256];
    __shared__ uint32_t smm[2];
    __shared__ uint32_t lastf;
    int t = threadIdx.x;
    if (t < FB) lh[t] = 0u;
    __syncthreads();

    const float4* im4 = (const float4*)im;
    int tid = blockIdx.x * 1024 + t;
    // hoisted loads: 12 independent float4 in flight before any compute (round-4 proven)
    float4 A0 = im4[tid],              B0 = im4[tid + N4],              C0 = im4[tid + 2 * N4];
    float4 A1 = im4[tid + STRIDE],     B1 = im4[tid + STRIDE + N4],     C1 = im4[tid + STRIDE + 2 * N4];
    float4 A2 = im4[tid + 2 * STRIDE], B2 = im4[tid + 2 * STRIDE + N4], C2 = im4[tid + 2 * STRIDE + 2 * N4];
    float4 A3 = im4[tid + 3 * STRIDE], B3 = im4[tid + 3 * STRIDE + N4], C3 = im4[tid + 3 * STRIDE + 2 * N4];

#define HBIN(a, b, c) { \
        float m0 = fmaxf(a.x, fmaxf(b.x, c.x)); \
        float m1 = fmaxf(a.y, fmaxf(b.y, c.y)); \
        float m2 = fmaxf(a.z, fmaxf(b.z, c.z)); \
        float m3 = fmaxf(a.w, fmaxf(b.w, c.w)); \
        int b0 = (int)(m0 * (float)FB); b0 = b0 < 0 ? 0 : (b0 > FB - 1 ? FB - 1 : b0); \
        int b1 = (int)(m1 * (float)FB); b1 = b1 < 0 ? 0 : (b1 > FB - 1 ? FB - 1 : b1); \
        int b2 = (int)(m2 * (float)FB); b2 = b2 < 0 ? 0 : (b2 > FB - 1 ? FB - 1 : b2); \
        int b3 = (int)(m3 * (float)FB); b3 = b3 < 0 ? 0 : (b3 > FB - 1 ? FB - 1 : b3); \
        atomicAdd(&lh[b0], 1u); atomicAdd(&lh[b1], 1u); \
        atomicAdd(&lh[b2], 1u); atomicAdd(&lh[b3], 1u); }
    HBIN(A0, B0, C0)
    HBIN(A1, B1, C1)
    HBIN(A2, B2, C2)
    HBIN(A3, B3, C3)
#undef HBIN

    __syncthreads();
    // paired 64-bit flush (halves device RMWs; per-bin totals < 2^32 so no cross-carry),
    // rotated start per block to spread same-line queueing (round-5 proven numerics).
    if (t < 256) {
        int pr = (t + blockIdx.x * 7) & 255;
        unsigned long long v = (unsigned long long)lh[2 * pr]
                             | ((unsigned long long)lh[2 * pr + 1] << 32);
        if (v) atomicAdd((unsigned long long*)&ctl[2 * pr], v);
    }
    __syncthreads();
    if (t == 0) {
        __threadfence();
        lastf = (atomicAdd(&ctl[518], 1u) == G1H - 1) ? 1u : 0u;
    }
    __syncthreads();
    if (!lastf) return;

    // ---- last block only: derive 256-bin cdf (exact numerics of the original cdf_k) ----
    if (t < FB) lh[t] = atomicAdd(&ctl[t], 0u);   // device-scope read: sees all flush atomics
    if (t < 256) sc[t] = 0u;
    if (t == 0) { smm[0] = FB; smm[1] = 0u; }
    __syncthreads();
    if (t < FB && lh[t]) { atomicMin(&smm[0], (uint32_t)t); atomicMax(&smm[1], (uint32_t)t); }
    __syncthreads();
    float gmin = (float)smm[0] * (1.0f / (float)FB);         // left edge of first nonempty fine bin
    float gmax = (float)(smm[1] + 1u) * (1.0f / (float)FB);  // right edge of last nonempty fine bin
    float inv_dw = 256.0f / (gmax - gmin);
    if (t < FB && lh[t]) {
        float c = ((float)t + 0.5f) * (1.0f / (float)FB);    // fine-bin center
        int q = (int)((c - gmin) * inv_dw);
        q = q < 0 ? 0 : (q > 255 ? 255 : q);
        atomicAdd(&sc[q], lh[t]);
    }
    __syncthreads();
    // inclusive integer scan -> cdf (barriers unconditional for all 1024 threads)
    for (int d = 1; d < 256; d <<= 1) {
        uint32_t v = (t < 256 && t >= d) ? sc[t - d] : 0u;
        __syncthreads();
        if (t < 256) sc[t] += v;
        __syncthreads();
    }
    float* cf = (float*)ctl;
    if (t < 256) cf[t] = (float)((double)sc[t] * (1.0 / (double)HW));
    if (t == 0) { cf[256] = gmin; cf[257] = gmax; }
}

// ---------------- K2: fused main pass + finalize ----------------
__device__ __forceinline__ void px(float r0, float r1, float r2,
                                   float i0, float i1, float i2, float l,
                                   float& rgp, float& lp,
                                   const float* __restrict__ scdf, float gmin, float inv_dw,
                                   float& a0, float& a1, float& a2,
                                   float& a3, float& a4, float& a5) {
    a0 += fabsf(r0 * l - i0) + fabsf(r1 * l - i1) + fabsf(r2 * l - i2);
    float rmax = fmaxf(r0, fmaxf(r1, r2));
    float imax = fmaxf(i0, fmaxf(i1, i2));
    float t = (imax - gmin) * inv_dw;
    t = fmaxf(t, 0.f);
    int bi = (int)t;
    float eq;
    if (bi >= 255) eq = scdf[255];
    else {
        float fr = t - (float)bi;
        eq = scdf[bi] + fr * (scdf[bi + 1] - scdf[bi]);
    }
    a1 += fabsf(rmax - eq);
    float rg = gray_pil(r0, r1, r2);
    a3 += rg;
    a5 += l * __expf(-10.f * rg);
    float drg = fabsf(rg - rgp);
    a2 += drg;
    a4 += fabsf(l - lp) * __expf(-10.f * drg);
    rgp = rg;
    lp = l;
}

// Round-2 work mapping (512 blocks x 1024 thr, one 2-row strip/thread), but with ALL 18
// float4 loads hoisted above all consumption for MLP (~288 outstanding lines/CU at 1 block/CU).
// launch_bounds(1024,1): allows VGPR ~110 without spills (arg2=4 would clamp to 64 -> spill, R4).
__global__ __launch_bounds__(1024, 1)
void main_k(const float* __restrict__ im, const float* __restrict__ R,
            const float* __restrict__ L, uint32_t* __restrict__ ctl,
            float* __restrict__ part, int use_part,
            float* __restrict__ out) {
    __shared__ float scdf[256];
    __shared__ float red[6][16];
    __shared__ uint32_t lastf;
    int t = threadIdx.x;

    const float* cf = (const float*)ctl;
    if (t < 256) scdf[t] = cf[t];
    float gmin = cf[256];
    float gmax = cf[257];
    float inv_dw = 256.0f / (gmax - gmin);
    __syncthreads();

    int w = (t & 511) * 4;                    // 4 adjacent columns per thread
    int h0 = blockIdx.x * 4 + ((t >> 9) * 2); // 2-row strip per thread (rows h0, h0+1)
    const int p1 = h0 * WW + w;
    const int p2 = p1 + WW;

    // ---- issue ALL loads before ANY consumption (18 independent float4) ----
    float4 Pa, Pb, Pc, Pl;
    if (h0 > 0) {                              // wave-uniform branch (t>>9 constant per wave)
        int pp = p1 - WW;
        Pa = *(const float4*)(R + pp);
        Pb = *(const float4*)(R + pp + HW);
        Pc = *(const float4*)(R + pp + 2 * HW);
        Pl = *(const float4*)(L + pp);
    }
    float4 r0a = *(const float4*)(R + p1);
    float4 r0b = *(const float4*)(R + p1 + HW);
    float4 r0c = *(const float4*)(R + p1 + 2 * HW);
    float4 i0a = *(const float4*)(im + p1);
    float4 i0b = *(const float4*)(im + p1 + HW);
    float4 i0c = *(const float4*)(im + p1 + 2 * HW);
    float4 l0  = *(const float4*)(L + p1);
    float4 r1a = *(const float4*)(R + p2);
    float4 r1b = *(const float4*)(R + p2 + HW);
    float4 r1c = *(const float4*)(R + p2 + 2 * HW);
    float4 i1a = *(const float4*)(im + p2);
    float4 i1b = *(const float4*)(im + p2 + HW);
    float4 i1c = *(const float4*)(im + p2 + 2 * HW);
    float4 l1  = *(const float4*)(L + p2);

    float a0 = 0.f, a1 = 0.f, a2 = 0.f, a3 = 0.f, a4 = 0.f, a5 = 0.f;
    float rgp[4], lp[4];
    if (h0 > 0) {
        rgp[0] = gray_pil(Pa.x, Pb.x, Pc.x); lp[0] = Pl.x;
        rgp[1] = gray_pil(Pa.y, Pb.y, Pc.y); lp[1] = Pl.y;
        rgp[2] = gray_pil(Pa.z, Pb.z, Pc.z); lp[2] = Pl.z;
        rgp[3] = gray_pil(Pa.w, Pb.w, Pc.w); lp[3] = Pl.w;
    } else {
        rgp[0] = rgp[1] = rgp[2] = rgp[3] = 0.f;
        lp[0] = lp[1] = lp[2] = lp[3] = 0.f;
    }

    // row h0
    px(r0a.x, r0b.x, r0c.x, i0a.x, i0b.x, i0c.x, l0.x, rgp[0], lp[0], scdf, gmin, inv_dw, a0, a1, a2, a3, a4, a5);
    px(r0a.y, r0b.y, r0c.y, i0a.y, i0b.y, i0c.y, l0.y, rgp[1], lp[1], scdf, gmin, inv_dw, a0, a1, a2, a3, a4, a5);
    px(r0a.z, r0b.z, r0c.z, i0a.z, i0b.z, i0c.z, l0.z, rgp[2], lp[2], scdf, gmin, inv_dw, a0, a1, a2, a3, a4, a5);
    px(r0a.w, r0b.w, r0c.w, i0a.w, i0b.w, i0c.w, l0.w, rgp[3], lp[3], scdf, gmin, inv_dw, a0, a1, a2, a3, a4, a5);
    // row h0+1
    px(r1a.x, r1b.x, r1c.x, i1a.x, i1b.x, i1c.x, l1.x, rgp[0], lp[0], scdf, gmin, inv_dw, a0, a1, a2, a3, a4, a5);
    px(r1a.y, r1b.y, r1c.y, i1a.y, i1b.y, i1c.y, l1.y, rgp[1], lp[1], scdf, gmin, inv_dw, a0, a1, a2, a3, a4, a5);
    px(r1a.z, r1b.z, r1c.z, i1a.z, i1b.z, i1c.z, l1.z, rgp[2], lp[2], scdf, gmin, inv_dw, a0, a1, a2, a3, a4, a5);
    px(r1a.w, r1b.w, r1c.w, i1a.w, i1b.w, i1c.w, l1.w, rgp[3], lp[3], scdf, gmin, inv_dw, a0, a1, a2, a3, a4, a5);

    if (h0 + 2 == HH) {  // boundary at h = 2048: |0 - x[2047]|
#pragma unroll
        for (int j = 0; j < 4; ++j) {
            a2 += rgp[j];
            a4 += lp[j] * __expf(-10.f * rgp[j]);
        }
    }

    for (int off = 32; off; off >>= 1) {
        a0 += __shfl_down(a0, off);
        a1 += __shfl_down(a1, off);
        a2 += __shfl_down(a2, off);
        a3 += __shfl_down(a3, off);
        a4 += __shfl_down(a4, off);
        a5 += __shfl_down(a5, off);
    }
    int lane = t & 63, wv = t >> 6;
    if (lane == 0) {
        red[0][wv] = a0; red[1][wv] = a1; red[2][wv] = a2;
        red[3][wv] = a3; red[4][wv] = a4; red[5][wv] = a5;
    }
    __syncthreads();
    if (t == 0) {
        float s0 = 0, s1 = 0, s2 = 0, s3 = 0, s4 = 0, s5 = 0;
        for (int k = 0; k < 16; k++) {
            s0 += red[0][k]; s1 += red[1][k]; s2 += red[2][k];
            s3 += red[3][k]; s4 += red[4][k]; s5 += red[5][k];
        }
        if (use_part) {
            // chain-free: distinct slot per block (round-4 proven pattern)
            float* pp = part + blockIdx.x * 6;
            atomicExch(&pp[0], s0); atomicExch(&pp[1], s1); atomicExch(&pp[2], s2);
            atomicExch(&pp[3], s3); atomicExch(&pp[4], s4); atomicExch(&pp[5], s5);
        } else {
            float* acc = (float*)(ctl + 512);
            atomicAdd(&acc[0], s0); atomicAdd(&acc[1], s1); atomicAdd(&acc[2], s2);
            atomicAdd(&acc[3], s3); atomicAdd(&acc[4], s4); atomicAdd(&acc[5], s5);
        }
        __threadfence();
        lastf = (atomicAdd(&ctl[518], 1u) == (uint32_t)(G1H + G3M - 1)) ? 1u : 0u;
    }
    __syncthreads();
    if (!lastf) return;

    // ---- last block: final combine ----
    if (use_part) {
        float s0 = 0.f, s1 = 0.f, s2 = 0.f, s3 = 0.f, s4 = 0.f, s5 = 0.f;
        if (t < G3M) {
            float* pp = part + t * 6;
            s0 = atomicAdd(&pp[0], 0.f); s1 = atomicAdd(&pp[1], 0.f); s2 = atomicAdd(&pp[2], 0.f);
            s3 = atomicAdd(&pp[3], 0.f); s4 = atomicAdd(&pp[4], 0.f); s5 = atomicAdd(&pp[5], 0.f);
        }
        for (int off = 32; off; off >>= 1) {
            s0 += __shfl_down(s0, off);
            s1 += __shfl_down(s1, off);
            s2 += __shfl_down(s2, off);
            s3 += __shfl_down(s3, off);
            s4 += __shfl_down(s4, off);
            s5 += __shfl_down(s5, off);
        }
        if (lane == 0) {
            red[0][wv] = s0; red[1][wv] = s1; red[2][wv] = s2;
            red[3][wv] = s3; red[4][wv] = s4; red[5][wv] = s5;
        }
        __syncthreads();
        if (t == 0) {
            float v0 = 0, v1 = 0, v2 = 0, v3 = 0, v4 = 0, v5 = 0;
            for (int k = 0; k < 16; k++) {
                v0 += red[0][k]; v1 += red[1][k]; v2 += red[2][k];
                v3 += red[3][k]; v4 += red[4][k]; v5 += red[5][k];
            }
            float recon_low = v0 / (3.0f * (float)HW);
            float recon_eq = v1 / (float)HW;
            float denom = 2.0f * 2049.0f * 2050.0f;
            float r_smooth = (v2 + 2.f * v3) / denom;
            float ismooth = (v4 + 2.f * v5) / denom;
            out[0] = recon_low + 0.1f * ismooth + 0.1f * recon_eq + 0.01f * r_smooth;
        }
    } else {
        if (t == 0) {
            float* acc = (float*)(ctl + 512);
            float v0 = atomicAdd(&acc[0], 0.f);
            float v1 = atomicAdd(&acc[1], 0.f);
            float v2 = atomicAdd(&acc[2], 0.f);
            float v3 = atomicAdd(&acc[3], 0.f);
            float v4 = atomicAdd(&acc[4], 0.f);
            float v5 = atomicAdd(&acc[5], 0.f);
            float recon_low = v0 / (3.0f * (float)HW);
            float recon_eq = v1 / (float)HW;
            float denom = 2.0f * 2049.0f * 2050.0f;
            float r_smooth = (v2 + 2.f * v3) / denom;
            float ismooth = (v4 + 2.f * v5) / denom;
            out[0] = recon_low + 0.1f * ismooth + 0.1f * recon_eq + 0.01f * r_smooth;
        }
    }
}

extern "C" void kernel_launch(void* const* d_in, const int* in_sizes, int n_in,
                              void* d_out, int out_size, void* d_ws, size_t ws_size,
                              hipStream_t stream) {
    const float* im = (const float*)d_in[0];
    const float* R = (const float*)d_in[1];
    const float* L = (const float*)d_in[2];
    float* out = (float*)d_out;
    uint32_t* ctl = (uint32_t*)d_ws;

    // partials region: words [520 .. 520 + 6*G3M) -> 14368 B total; gate on actual ws_size
    int use_part = (ws_size >= (size_t)((520 + 6 * G3M) * 4 + 32)) ? 1 : 0;
    float* part = (float*)(ctl + 520);

    hipMemsetAsync(d_ws, 0, 519 * 4, stream);  // graph-capturable memset node
    hipLaunchKernelGGL(hist_k, dim3(G1H), dim3(1024), 0, stream, im, ctl);
    hipLaunchKernelGGL(main_k, dim3(G3M), dim3(1024), 0, stream, im, R, L, ctl, part, use_part, out);
}